// Round 7
// baseline (1500.557 us; speedup 1.0000x reference)
//
#include <hip/hip_runtime.h>
#include <hip/hip_bf16.h>

#define N_NODES 100000
#define N_EDGES 1600000
#define F_IN    700
#define KROW    704         // padded Wt row length (halves), zeros for k>=700
#define NKB0    22          // ceil(700/32)
#define HDIM    128
#define SCAN_B  256
#define NB_SCAN ((N_NODES + SCAN_B - 1) / SCAN_B)   // 391

typedef _Float16 half8 __attribute__((ext_vector_type(8)));
typedef _Float16 half4 __attribute__((ext_vector_type(4)));
typedef float floatx4 __attribute__((ext_vector_type(4)));

// ---------------------------------------------------------------- CSR build
__global__ void count_edges(const int* __restrict__ graph, int* __restrict__ cnt) {
    int e = blockIdx.x * blockDim.x + threadIdx.x;
    if (e < N_EDGES) atomicAdd(&cnt[graph[2 * e + 1]], 1);
}

__global__ void scan1(const int* __restrict__ cnt, int* __restrict__ incl,
                      int* __restrict__ blk) {
    __shared__ int s[SCAN_B];
    int tid = threadIdx.x;
    int i = blockIdx.x * SCAN_B + tid;
    s[tid] = (i < N_NODES) ? cnt[i] : 0;
    __syncthreads();
    for (int off = 1; off < SCAN_B; off <<= 1) {
        int t = (tid >= off) ? s[tid - off] : 0;
        __syncthreads();
        s[tid] += t;
        __syncthreads();
    }
    if (i < N_NODES) incl[i] = s[tid];
    if (tid == SCAN_B - 1) blk[blockIdx.x] = s[tid];
}

__global__ void scan2(const int* __restrict__ blk, int* __restrict__ blkoff) {
    __shared__ int s[512];
    int tid = threadIdx.x;
    s[tid] = (tid < NB_SCAN) ? blk[tid] : 0;
    __syncthreads();
    for (int off = 1; off < 512; off <<= 1) {
        int t = (tid >= off) ? s[tid - off] : 0;
        __syncthreads();
        s[tid] += t;
        __syncthreads();
    }
    if (tid < NB_SCAN) blkoff[tid] = (tid == 0) ? 0 : s[tid - 1];
}

__global__ void scan3(const int* __restrict__ incl, const int* __restrict__ blkoff,
                      int* __restrict__ row_ptr) {
    int i = blockIdx.x * SCAN_B + threadIdx.x;
    if (i < N_NODES) {
        row_ptr[i + 1] = incl[i] + blkoff[i >> 8];
        if (i == 0) row_ptr[0] = 0;
    }
}

__global__ void fill_edges(const int* __restrict__ graph, const int* __restrict__ row_ptr,
                           int* __restrict__ cursor, int* __restrict__ esrc) {
    int e = blockIdx.x * blockDim.x + threadIdx.x;
    if (e < N_EDGES) {
        int src = graph[2 * e];
        int dst = graph[2 * e + 1];
        esrc[row_ptr[dst] + atomicAdd(&cursor[dst], 1)] = src;
    }
}

// -------------------- weight packs: plain transpose, fp16 (no LDS => no swizzle)
// Wt0[n][k] (256 x 704): n<128 -> Wneigh col n ; n>=128 -> Wself col n-128
__global__ void build_wt0(const float* __restrict__ Wn, const float* __restrict__ Ws,
                          _Float16* __restrict__ out) {
    int idx = blockIdx.x * blockDim.x + threadIdx.x;
    if (idx >= 256 * KROW) return;
    int n = idx / KROW, k = idx % KROW;
    float v = 0.0f;
    if (k < F_IN) v = (n < 128) ? Wn[k * 128 + n] : Ws[k * 128 + (n - 128)];
    out[idx] = (_Float16)v;
}

// Wtl[l][n][k] (3 x 256 x 128)
__global__ void build_wtl(const float* __restrict__ Wn, const float* __restrict__ Ws,
                          _Float16* __restrict__ out) {
    int idx = blockIdx.x * blockDim.x + threadIdx.x;
    if (idx >= 3 * 256 * 128) return;
    int l = idx / (256 * 128);
    int rem = idx % (256 * 128);
    int n = rem / 128, k = rem % 128;
    float v = (n < 128) ? Wn[l * 16384 + k * 128 + n]
                        : Ws[l * 16384 + k * 128 + (n - 128)];
    out[idx] = (_Float16)v;
}

// --------------- layer-0 register-direct GEMM: no LDS, no barriers.
// Per-wave A frags loaded straight from global fp32 (cvt in reg), B frags
// from L2-resident Wt0. Distance-1 register double buffer; compiler emits
// fine-grained per-wave vmcnt (AITER pattern) instead of barrier drains.
// block bx: M-tile bx>>1 (128 rows), nh = bx&1 (0: Cn fp16, 1: Cs fp32+bias)
__global__ __launch_bounds__(256) void gemm0_reg(
    const float* __restrict__ A, int M,
    const _Float16* __restrict__ Wt, const float* __restrict__ bias,
    const float* __restrict__ zbuf,
    _Float16* __restrict__ Cn, float* __restrict__ Cs) {
    int tid = threadIdx.x;
    int wave = tid >> 6, lane = tid & 63;
    int lm = lane & 15, quad = lane >> 4;
    int wm = wave >> 1, wn = wave & 1;      // 2x2 waves: 64 rows x 64 cols
    int bx = blockIdx.x;
    long row0 = (long)(bx >> 1) * 128;
    int nh = bx & 1;

    const float* ap[4];
    bool rv[4];
    #pragma unroll
    for (int i = 0; i < 4; i++) {
        long r = row0 + wm * 64 + i * 16 + lm;
        rv[i] = (r < M);
        ap[i] = A + (rv[i] ? r : 0) * (long)F_IN;
    }
    const _Float16* bp[4];
    #pragma unroll
    for (int j = 0; j < 4; j++) {
        int brow = nh * 128 + wn * 64 + j * 16 + lm;
        bp[j] = Wt + (size_t)brow * KROW;
    }

    floatx4 acc[4][4] = {};
    floatx4 a0[4], a1[4];
    half8 bnx[4];

    {   // prologue: kb = 0 (k = quad*8 .. +8, always valid: <= 32 <= 700)
        int k = quad * 8;
        #pragma unroll
        for (int i = 0; i < 4; i++) {
            const float* s = rv[i] ? (ap[i] + k) : zbuf;
            a0[i] = *(const floatx4*)s;
            a1[i] = *(const floatx4*)(rv[i] ? (ap[i] + k + 4) : zbuf);
        }
        #pragma unroll
        for (int j = 0; j < 4; j++) bnx[j] = *(const half8*)(bp[j] + k);
    }

    for (int kb = 0; kb < NKB0; kb++) {
        half8 af[4], bf[4];
        #pragma unroll
        for (int i = 0; i < 4; i++) {
            af[i][0] = (_Float16)a0[i][0]; af[i][1] = (_Float16)a0[i][1];
            af[i][2] = (_Float16)a0[i][2]; af[i][3] = (_Float16)a0[i][3];
            af[i][4] = (_Float16)a1[i][0]; af[i][5] = (_Float16)a1[i][1];
            af[i][6] = (_Float16)a1[i][2]; af[i][7] = (_Float16)a1[i][3];
        }
        #pragma unroll
        for (int j = 0; j < 4; j++) bf[j] = bnx[j];

        if (kb + 1 < NKB0) {
            int k = (kb + 1) * 32 + quad * 8;
            bool ok0 = (k + 4 <= F_IN);      // false only for kb=21, quad=3 tail
            bool ok1 = (k + 8 <= F_IN);
            #pragma unroll
            for (int i = 0; i < 4; i++) {
                a0[i] = *(const floatx4*)((rv[i] && ok0) ? (ap[i] + k) : zbuf);
                a1[i] = *(const floatx4*)((rv[i] && ok1) ? (ap[i] + k + 4) : zbuf);
            }
            // Wt is zero-padded for k>=700, so garbage/zero A tail contributes 0
            #pragma unroll
            for (int j = 0; j < 4; j++) bnx[j] = *(const half8*)(bp[j] + k);
        }

        #pragma unroll
        for (int j = 0; j < 4; j++)
            #pragma unroll
            for (int i = 0; i < 4; i++)
                acc[i][j] = __builtin_amdgcn_mfma_f32_16x16x32_f16(af[i], bf[j], acc[i][j], 0, 0, 0);
    }

    #pragma unroll
    for (int i = 0; i < 4; i++) {
        long r0 = row0 + wm * 64 + i * 16 + quad * 4;
        #pragma unroll
        for (int j = 0; j < 4; j++) {
            int c = wn * 64 + j * 16 + lm;
            if (nh) {
                float badd = bias[c];
                #pragma unroll
                for (int rr = 0; rr < 4; rr++) {
                    long r = r0 + rr;
                    if (r < M) Cs[r * HDIM + c] = acc[i][j][rr] + badd;
                }
            } else {
                #pragma unroll
                for (int rr = 0; rr < 4; rr++) {
                    long r = r0 + rr;
                    if (r < M) Cn[r * HDIM + c] = (_Float16)acc[i][j][rr];
                }
            }
        }
    }
}

// --------------- K=128 register-direct GEMM (fp16 A), no LDS / barriers
__global__ __launch_bounds__(256) void gemm16_reg(
    const _Float16* __restrict__ A, int M,
    const _Float16* __restrict__ Wt, const float* __restrict__ bias,
    const _Float16* __restrict__ zbuf16,
    _Float16* __restrict__ Cn, float* __restrict__ Cs) {
    int tid = threadIdx.x;
    int wave = tid >> 6, lane = tid & 63;
    int lm = lane & 15, quad = lane >> 4;
    int wm = wave >> 1, wn = wave & 1;
    int bx = blockIdx.x;
    long row0 = (long)(bx >> 1) * 128;
    int nh = bx & 1;

    const _Float16* ap[4];
    #pragma unroll
    for (int i = 0; i < 4; i++) {
        long r = row0 + wm * 64 + i * 16 + lm;
        ap[i] = (r < M) ? (A + r * (long)HDIM) : zbuf16;   // zbuf16: 32B zeros, k stays 0-based below via valid flag
    }
    bool rv[4];
    #pragma unroll
    for (int i = 0; i < 4; i++) {
        long r = row0 + wm * 64 + i * 16 + lm;
        rv[i] = (r < M);
        ap[i] = A + (rv[i] ? r : 0) * (long)HDIM;
    }
    const _Float16* bp[4];
    #pragma unroll
    for (int j = 0; j < 4; j++) {
        int brow = nh * 128 + wn * 64 + j * 16 + lm;
        bp[j] = Wt + (size_t)brow * HDIM;
    }

    floatx4 acc[4][4] = {};
    half8 an[4], bnx[4];

    {   int k = quad * 8;
        #pragma unroll
        for (int i = 0; i < 4; i++)
            an[i] = *(const half8*)(rv[i] ? (ap[i] + k) : zbuf16);
        #pragma unroll
        for (int j = 0; j < 4; j++) bnx[j] = *(const half8*)(bp[j] + k);
    }

    for (int kb = 0; kb < 4; kb++) {
        half8 af[4], bf[4];
        #pragma unroll
        for (int i = 0; i < 4; i++) af[i] = an[i];
        #pragma unroll
        for (int j = 0; j < 4; j++) bf[j] = bnx[j];

        if (kb + 1 < 4) {
            int k = (kb + 1) * 32 + quad * 8;
            #pragma unroll
            for (int i = 0; i < 4; i++)
                an[i] = *(const half8*)(rv[i] ? (ap[i] + k) : zbuf16);
            #pragma unroll
            for (int j = 0; j < 4; j++) bnx[j] = *(const half8*)(bp[j] + k);
        }

        #pragma unroll
        for (int j = 0; j < 4; j++)
            #pragma unroll
            for (int i = 0; i < 4; i++)
                acc[i][j] = __builtin_amdgcn_mfma_f32_16x16x32_f16(af[i], bf[j], acc[i][j], 0, 0, 0);
    }

    #pragma unroll
    for (int i = 0; i < 4; i++) {
        long r0 = row0 + wm * 64 + i * 16 + quad * 4;
        #pragma unroll
        for (int j = 0; j < 4; j++) {
            int c = wn * 64 + j * 16 + lm;
            if (nh) {
                float badd = bias[c];
                #pragma unroll
                for (int rr = 0; rr < 4; rr++) {
                    long r = r0 + rr;
                    if (r < M) Cs[r * HDIM + c] = acc[i][j][rr] + badd;
                }
            } else {
                #pragma unroll
                for (int rr = 0; rr < 4; rr++) {
                    long r = r0 + rr;
                    if (r < M) Cn[r * HDIM + c] = (_Float16)acc[i][j][rr];
                }
            }
        }
    }
}

// ------------------------------------------------------------- aggregation
__global__ __launch_bounds__(256) void aggregate_w(
    const _Float16* __restrict__ hn, const int* __restrict__ row_ptr,
    const int* __restrict__ esrc, float* __restrict__ pre) {
    int wave = threadIdx.x >> 6, lane = threadIdx.x & 63;
    int n = blockIdx.x * 4 + wave;
    if (n >= N_NODES) return;
    int start = row_ptr[n], end = row_ptr[n + 1];
    int eg = lane >> 4;            // edge slot 0..3
    int c8 = (lane & 15) * 8;      // channel group

    float acc[8] = {};
    for (int base = start; base < end; base += 16) {
        #pragma unroll
        for (int u = 0; u < 4; u++) {
            int e = base + u * 4 + eg;
            if (e < end) {
                int s = esrc[e];
                half8 v = *(const half8*)&hn[(size_t)s * HDIM + c8];
                #pragma unroll
                for (int i = 0; i < 8; i++) acc[i] += (float)v[i];
            }
        }
    }
    #pragma unroll
    for (int i = 0; i < 8; i++) {
        acc[i] += __shfl_xor(acc[i], 16, 64);
        acc[i] += __shfl_xor(acc[i], 32, 64);
    }
    if (eg == 0) {
        float rd = 1.0f / (float)max(end - start, 1);
        size_t off = (size_t)n * HDIM + c8;
        float4 p0 = *(float4*)&pre[off];
        float4 p1 = *(float4*)&pre[off + 4];
        p0.x += acc[0] * rd; p0.y += acc[1] * rd;
        p0.z += acc[2] * rd; p0.w += acc[3] * rd;
        p1.x += acc[4] * rd; p1.y += acc[5] * rd;
        p1.z += acc[6] * rd; p1.w += acc[7] * rd;
        *(float4*)&pre[off]     = p0;
        *(float4*)&pre[off + 4] = p1;
    }
}

// --------------------------------------------------------------- batch norm
__global__ void bn_stats(const float* __restrict__ P, float* __restrict__ gsum,
                         float* __restrict__ gsumsq, int M, int C) {
    int tid = threadIdx.x;
    int c = tid % C;
    int rpb = 256 / C;
    float s = 0.0f, s2 = 0.0f;
    for (int r = blockIdx.x * rpb + tid / C; r < M; r += gridDim.x * rpb) {
        float v = P[(size_t)r * C + c];
        s += v; s2 += v * v;
    }
    __shared__ float ss[256], ss2[256];
    ss[tid] = s; ss2[tid] = s2;
    __syncthreads();
    for (int off = 128; off >= C; off >>= 1) {
        if (tid < off) { ss[tid] += ss[tid + off]; ss2[tid] += ss2[tid + off]; }
        __syncthreads();
    }
    if (tid < C) {
        atomicAdd(&gsum[tid], ss[tid]);
        atomicAdd(&gsumsq[tid], ss2[tid]);
    }
}

// h16 = fp16(relu(P*scale+shift [+ res16])), scale/shift derived per-block
__global__ void bn_apply16(const float* __restrict__ P, const _Float16* __restrict__ res16,
                           _Float16* __restrict__ out16,
                           const float* __restrict__ gsum, const float* __restrict__ gsumsq,
                           const float* __restrict__ gamma, const float* __restrict__ beta,
                           int M, int total4, int Cdiv4) {
    __shared__ float ssc[HDIM], ssh[HDIM];
    int tid = threadIdx.x;
    int C = Cdiv4 * 4;
    if (tid < C) {
        float mean = gsum[tid] / (float)M;
        float var = gsumsq[tid] / (float)M - mean * mean;
        float sc = rsqrtf(var + 1e-5f) * gamma[tid];
        ssc[tid] = sc;
        ssh[tid] = beta[tid] - mean * sc;
    }
    __syncthreads();
    for (int f = blockIdx.x * blockDim.x + tid; f < total4;
         f += gridDim.x * blockDim.x) {
        int c4 = (f % Cdiv4) * 4;
        float4 v = ((const float4*)P)[f];
        v.x = v.x * ssc[c4 + 0] + ssh[c4 + 0];
        v.y = v.y * ssc[c4 + 1] + ssh[c4 + 1];
        v.z = v.z * ssc[c4 + 2] + ssh[c4 + 2];
        v.w = v.w * ssc[c4 + 3] + ssh[c4 + 3];
        if (res16) {
            half4 rv = *(const half4*)&res16[(size_t)f * 4];
            v.x += (float)rv[0]; v.y += (float)rv[1];
            v.z += (float)rv[2]; v.w += (float)rv[3];
        }
        half4 h;
        h[0] = (_Float16)fmaxf(v.x, 0.0f); h[1] = (_Float16)fmaxf(v.y, 0.0f);
        h[2] = (_Float16)fmaxf(v.z, 0.0f); h[3] = (_Float16)fmaxf(v.w, 0.0f);
        *(half4*)&out16[(size_t)f * 4] = h;
    }
}

// --------------------------------------------------------------- MLP head
__global__ __launch_bounds__(256) void mlp_gemm(const _Float16* __restrict__ H,
                                                const float* __restrict__ W1,
                                                const float* __restrict__ b1,
                                                float* __restrict__ Z, int M) {
    __shared__ float hs[64 * 132];
    __shared__ float ws[128 * 64];
    int tid = threadIdx.x;
    int tx = tid & 15;
    int ty = tid >> 4;
    int row0 = blockIdx.x * 64;

    #pragma unroll
    for (int t = 0; t < 8; t++) {
        int f = tid + t * 256;
        int r = f >> 4, c4 = (f & 15) * 4;
        *(float4*)&ws[r * 64 + c4] = *(const float4*)&W1[r * 64 + c4];
    }
    #pragma unroll
    for (int t = 0; t < 4; t++) {
        int f = tid + t * 256;
        int r = f >> 4, c8 = (f & 15) * 8;
        int gr = row0 + r;
        if (gr < M) {
            half8 hv = *(const half8*)&H[(size_t)gr * HDIM + c8];
            #pragma unroll
            for (int i = 0; i < 8; i++) hs[r * 132 + c8 + i] = (float)hv[i];
        } else {
            #pragma unroll
            for (int i = 0; i < 8; i++) hs[r * 132 + c8 + i] = 0.0f;
        }
    }
    __syncthreads();

    float acc[4][4] = {};
    for (int k = 0; k < 128; k++) {
        float a[4];
        #pragma unroll
        for (int i = 0; i < 4; i++) a[i] = hs[(ty * 4 + i) * 132 + k];
        float4 b4 = *(const float4*)&ws[k * 64 + tx * 4];
        #pragma unroll
        for (int i = 0; i < 4; i++) {
            acc[i][0] += a[i] * b4.x; acc[i][1] += a[i] * b4.y;
            acc[i][2] += a[i] * b4.z; acc[i][3] += a[i] * b4.w;
        }
    }
    float4 bb = *(const float4*)&b1[tx * 4];
    #pragma unroll
    for (int i = 0; i < 4; i++) {
        int r = row0 + ty * 4 + i;
        if (r < M) {
            float4 v = {acc[i][0] + bb.x, acc[i][1] + bb.y,
                        acc[i][2] + bb.z, acc[i][3] + bb.w};
            *(float4*)&Z[(size_t)r * 64 + tx * 4] = v;
        }
    }
}

// out[n] = relu(bn(Z[n,:])) . W2 + b2  — BN finalize+apply fused into the dot
__global__ void final_out(const float* __restrict__ Z,
                          const float* __restrict__ gsum, const float* __restrict__ gsumsq,
                          const float* __restrict__ gamma, const float* __restrict__ beta,
                          const float* __restrict__ W2, const float* __restrict__ b2,
                          float* __restrict__ out, int M) {
    __shared__ float ssc[64], ssh[64], sw[64];
    int tid = threadIdx.x;
    if (tid < 64) {
        float mean = gsum[tid] / (float)M;
        float var = gsumsq[tid] / (float)M - mean * mean;
        float sc = rsqrtf(var + 1e-5f) * gamma[tid];
        ssc[tid] = sc;
        ssh[tid] = beta[tid] - mean * sc;
        sw[tid] = W2[tid];
    }
    __syncthreads();
    int n = blockIdx.x * 4 + (tid >> 6);
    int lane = tid & 63;
    if (n >= N_NODES) return;
    float z = Z[(size_t)n * 64 + lane] * ssc[lane] + ssh[lane];
    z = fmaxf(z, 0.0f);
    float v = z * sw[lane];
    #pragma unroll
    for (int off = 32; off >= 1; off >>= 1) v += __shfl_down(v, off, 64);
    if (lane == 0) out[n] = v + b2[0];
}

// ------------------------------------------------------------------ driver
extern "C" void kernel_launch(void* const* d_in, const int* in_sizes, int n_in,
                              void* d_out, int out_size, void* d_ws, size_t ws_size,
                              hipStream_t stream) {
    const float* X       = (const float*)d_in[0];
    const int*   graph   = (const int*)d_in[1];
    const float* Wself0  = (const float*)d_in[2];
    const float* Wneigh0 = (const float*)d_in[3];
    const float* b0      = (const float*)d_in[4];
    const float* Wself   = (const float*)d_in[5];
    const float* Wneigh  = (const float*)d_in[6];
    const float* bvec    = (const float*)d_in[7];
    const float* bn_g    = (const float*)d_in[8];
    const float* bn_b    = (const float*)d_in[9];
    const float* W1      = (const float*)d_in[10];
    const float* b1      = (const float*)d_in[11];
    const float* bng1    = (const float*)d_in[12];
    const float* bnb1    = (const float*)d_in[13];
    const float* W2      = (const float*)d_in[14];
    const float* b2      = (const float*)d_in[15];
    float* out = (float*)d_out;

    size_t off = 0;
    auto alloc = [&](size_t bytes) {
        void* p = (char*)d_ws + off;
        off += (bytes + 255) & ~(size_t)255;
        return p;
    };
    int* cnt     = (int*)alloc(N_NODES * 4);
    int* cursor  = (int*)alloc(N_NODES * 4);
    int* row_ptr = (int*)alloc((N_NODES + 1) * 4);
    int* incl    = (int*)alloc(N_NODES * 4);
    int* blk     = (int*)alloc(NB_SCAN * 4);
    int* blkoff  = (int*)alloc(NB_SCAN * 4);
    int* esrc    = (int*)alloc((size_t)N_EDGES * 4);
    float*    pre   = (float*)alloc((size_t)N_NODES * HDIM * 4);    // 51.2 MB
    _Float16* h16A  = (_Float16*)alloc((size_t)N_NODES * HDIM * 2); // 25.6 MB
    _Float16* h16B  = (_Float16*)alloc((size_t)N_NODES * HDIM * 2);
    _Float16* hn16  = (_Float16*)alloc((size_t)N_NODES * HDIM * 2);
    float*    Z     = (float*)alloc((size_t)N_NODES * 64 * 4);
    _Float16* Wt0   = (_Float16*)alloc((size_t)256 * KROW * 2);
    _Float16* Wtl   = (_Float16*)alloc((size_t)3 * 256 * 128 * 2);
    float*    zbuf  = (float*)alloc(256);
    float* stats = (float*)alloc(256 * 4);
    float* gsum = stats, *gsumsq = stats + 128;

    const int EB = (N_EDGES + 255) / 256;
    const int GB = ((N_NODES + 127) / 128) * 2;   // 1564 (M-tiles x 2 N-halves)
    const int AGB = (N_NODES + 3) / 4;            // 25000

    // CSR build
    hipMemsetAsync(cnt, 0, N_NODES * 4, stream);
    hipMemsetAsync(cursor, 0, N_NODES * 4, stream);
    hipMemsetAsync(zbuf, 0, 256, stream);
    count_edges<<<EB, 256, 0, stream>>>(graph, cnt);
    scan1<<<NB_SCAN, SCAN_B, 0, stream>>>(cnt, incl, blk);
    scan2<<<1, 512, 0, stream>>>(blk, blkoff);
    scan3<<<NB_SCAN, SCAN_B, 0, stream>>>(incl, blkoff, row_ptr);
    fill_edges<<<EB, 256, 0, stream>>>(graph, row_ptr, cursor, esrc);

    // weight packs (plain fp16 transposes)
    build_wt0<<<(256 * KROW + 255) / 256, 256, 0, stream>>>(Wneigh0, Wself0, Wt0);
    build_wtl<<<(3 * 256 * 128 + 255) / 256, 256, 0, stream>>>(Wneigh, Wself, Wtl);

    _Float16* hc = h16A;
    _Float16* hx = h16B;

    // ---- layer 0 (K = 700, fp32 A, register-direct)
    gemm0_reg<<<GB, 256, 0, stream>>>(X, N_NODES, Wt0, b0, zbuf, hn16, pre);
    aggregate_w<<<AGB, 256, 0, stream>>>(hn16, row_ptr, esrc, pre);
    hipMemsetAsync(stats, 0, 256 * 4, stream);
    bn_stats<<<512, 256, 0, stream>>>(pre, gsum, gsumsq, N_NODES, 128);
    bn_apply16<<<1024, 256, 0, stream>>>(pre, nullptr, hc, gsum, gsumsq,
                                         bn_g, bn_b, N_NODES,
                                         N_NODES * HDIM / 4, HDIM / 4);

    // ---- layers 1..3 (K = 128, fp16 A, register-direct, fp16 residual)
    for (int l = 0; l < 3; l++) {
        gemm16_reg<<<GB, 256, 0, stream>>>(hc, N_NODES, Wtl + (size_t)l * 32768,
                                           bvec + l * HDIM, (const _Float16*)zbuf,
                                           hn16, pre);
        aggregate_w<<<AGB, 256, 0, stream>>>(hn16, row_ptr, esrc, pre);
        hipMemsetAsync(stats, 0, 256 * 4, stream);
        bn_stats<<<512, 256, 0, stream>>>(pre, gsum, gsumsq, N_NODES, 128);
        bn_apply16<<<1024, 256, 0, stream>>>(pre, hc, hx, gsum, gsumsq,
                                             bn_g + (l + 1) * HDIM,
                                             bn_b + (l + 1) * HDIM, N_NODES,
                                             N_NODES * HDIM / 4, HDIM / 4);
        _Float16* t = hc; hc = hx; hx = t;
    }

    // ---- MLP head (BN finalize+apply+ReLU fused into final_out)
    mlp_gemm<<<(N_NODES + 63) / 64, 256, 0, stream>>>(hc, W1, b1, Z, N_NODES);
    hipMemsetAsync(stats, 0, 256 * 4, stream);
    bn_stats<<<512, 256, 0, stream>>>(Z, gsum, gsumsq, N_NODES, 64);
    final_out<<<AGB, 256, 0, stream>>>(Z, gsum, gsumsq, bng1, bnb1, W2, b2,
                                       out, N_NODES);
}